// Round 5
// baseline (161.937 us; speedup 1.0000x reference)
//
#include <hip/hip_runtime.h>
#include <hip/hip_bf16.h>

typedef __attribute__((ext_vector_type(8))) __bf16 bf16x8;
typedef __attribute__((ext_vector_type(4))) float f32x4;
typedef unsigned short u16;

#define CIN   62
#define HW    224
#define NPIX  49

__device__ __forceinline__ u16 f2b(float f) {
    union { __hip_bfloat16 h; u16 u; } cv;
    cv.h = __float2bfloat16(f);
    return cv.u;
}

// LDS 64x64 bf16 tiles, row stride 64 elems (128B), XOR swizzle on 8-elem (16B) blocks
__device__ __forceinline__ bf16x8 ld8(const u16* buf, int row, int ecol) {
    int idx = (row << 6) + (ecol ^ ((row & 7) << 3));
    return *reinterpret_cast<const bf16x8*>(buf + idx);
}
__device__ __forceinline__ void st1(u16* buf, int row, int ecol, u16 v) {
    buf[(row << 6) + (ecol ^ ((row & 7) << 3))] = v;
}
__device__ __forceinline__ void st4(u16* buf, int row, int ecol, u16 a, u16 b, u16 c, u16 d) {
    int idx = (row << 6) + (ecol ^ ((row & 7) << 3));
    *reinterpret_cast<ushort4*>(buf + idx) = make_ushort4(a, b, c, d);
}

// wb rows 0..63   = G  = Wq^T Wk / 8   (S = X^T G X)
// wb rows 64..127 = Wf = Wp @ Wv       (Y = (Wf X) P^T)
__global__ void prep_weights(const float* __restrict__ wqkv, const float* __restrict__ wp,
                             u16* __restrict__ wb) {
    int t = blockIdx.x * 256 + threadIdx.x;   // 0 .. 128*64-1
    if (t >= 128 * 64) return;
    int o = t >> 6;
    int c = t & 63;
    float s = 0.0f;
    if (o < 64) {
        for (int m = 0; m < 64; ++m)
            s += wqkv[m * 64 + o] * wqkv[(64 + m) * 64 + c];
        s *= 0.125f;
    } else {
        int of = o - 64;
        if (of < CIN)
            for (int m = 0; m < 64; ++m)
                s += wp[of * 64 + m] * wqkv[(128 + m) * 64 + c];
    }
    wb[t] = f2b(s);
}

// One 64-thread wave per window. No __syncthreads anywhere: LDS is wave-private
// scratch, same-wave RAW ordering via lgkmcnt handled by the compiler.
__global__ __launch_bounds__(64, 3) void win_attn(
    const float* __restrict__ x, const u16* __restrict__ wb,
    const float* __restrict__ bproj, float* __restrict__ out)
{
    __shared__ __align__(16) u16 t1[64 * 64];  // T[j][g]  -> later P[i][j]
    __shared__ __align__(16) u16 t2[64 * 64];  // F[co][j]

    const int lane = threadIdx.x;
    const int lr   = lane & 15;
    const int lg   = lane >> 4;

    // XCD swizzle: each XCD gets one batch image (1024 consecutive windows)
    const int win = ((blockIdx.x & 7) << 10) | (blockIdx.x >> 3);
    const int b   = win >> 10;
    const int rem = win & 1023;
    const int hn  = rem >> 5;
    const int wn  = rem & 31;
    const int h0  = hn * 7, w0 = wn * 7;

    const size_t plane = (size_t)HW * HW;
    const float* xb = x + (size_t)b * CIN * plane;

    // ---- X fragments for all 4 pixel groups straight into registers.
    // xa[m] serves as: B-frag (col=pixel) for GEMM1, A-frag (row=pixel) for GEMM2.
    union { bf16x8 v; u16 u[8]; } xa[4][2];
#pragma unroll
    for (int m = 0; m < 4; ++m) {
        const int p = m * 16 + lr;
        const bool valid = p < NPIX;
        const int dh = p / 7, dw = p - dh * 7;
        const int h = h0 + dh, w = w0 + dw;
        const float cx = -1.0f + (2.0f / 223.0f) * (float)w;
        const float cy = -1.0f + (2.0f / 223.0f) * (float)h;
        const float* xp = xb + (size_t)h * HW + w;
#pragma unroll
        for (int ks = 0; ks < 2; ++ks)
#pragma unroll
            for (int e = 0; e < 8; ++e) {
                int c = ks * 32 + lg * 8 + e;
                float v = 0.0f;
                if (valid)
                    v = (c < CIN) ? xp[(size_t)c * plane] : ((c == 62) ? cx : cy);
                xa[m][ks].u[e] = f2b(v);
            }
    }

    const f32x4 fz = {0.f, 0.f, 0.f, 0.f};

    // ---- GEMM1-T: T(64g x 64px) = G @ X ; scatter T -> t1[j][g]
    {
        f32x4 a1[4][4];
#pragma unroll
        for (int m = 0; m < 4; ++m)
#pragma unroll
            for (int n = 0; n < 4; ++n) a1[m][n] = fz;
#pragma unroll
        for (int ks = 0; ks < 2; ++ks)
#pragma unroll
            for (int m = 0; m < 4; ++m) {
                bf16x8 ag = *reinterpret_cast<const bf16x8*>(
                    wb + (m * 16 + lr) * 64 + ks * 32 + lg * 8);
#pragma unroll
                for (int n = 0; n < 4; ++n)
                    a1[m][n] = __builtin_amdgcn_mfma_f32_16x16x32_bf16(ag, xa[n][ks].v, a1[m][n], 0, 0, 0);
            }
#pragma unroll
        for (int m = 0; m < 4; ++m)
#pragma unroll
            for (int n = 0; n < 4; ++n)
                st4(t1, n * 16 + lr, m * 16 + lg * 4,
                    f2b(a1[m][n][0]), f2b(a1[m][n][1]), f2b(a1[m][n][2]), f2b(a1[m][n][3]));
    }

    // ---- GEMM1-F: F(64co x 64px) = Wf @ X ; scatter F -> t2[co][j]
    {
        f32x4 a1[4][4];
#pragma unroll
        for (int m = 0; m < 4; ++m)
#pragma unroll
            for (int n = 0; n < 4; ++n) a1[m][n] = fz;
#pragma unroll
        for (int ks = 0; ks < 2; ++ks)
#pragma unroll
            for (int m = 0; m < 4; ++m) {
                bf16x8 af = *reinterpret_cast<const bf16x8*>(
                    wb + ((m + 4) * 16 + lr) * 64 + ks * 32 + lg * 8);
#pragma unroll
                for (int n = 0; n < 4; ++n)
                    a1[m][n] = __builtin_amdgcn_mfma_f32_16x16x32_bf16(af, xa[n][ks].v, a1[m][n], 0, 0, 0);
            }
#pragma unroll
        for (int m = 0; m < 4; ++m)
#pragma unroll
            for (int n = 0; n < 4; ++n)
#pragma unroll
                for (int r = 0; r < 4; ++r)
                    st1(t2, m * 16 + lg * 4 + r, n * 16 + lr, f2b(a1[m][n][r]));
    }

    // ---- GEMM2: S[i][j] = sum_g XT[i][g] T[j][g] ; A = xa (regs), B = t1
    f32x4 s4[4][4];
#pragma unroll
    for (int m = 0; m < 4; ++m)
#pragma unroll
        for (int n = 0; n < 4; ++n) s4[m][n] = fz;
#pragma unroll
    for (int ks = 0; ks < 2; ++ks)
#pragma unroll
        for (int n = 0; n < 4; ++n) {
            bf16x8 bt = ld8(t1, n * 16 + lr, ks * 32 + lg * 8);
#pragma unroll
            for (int m = 0; m < 4; ++m)
                s4[m][n] = __builtin_amdgcn_mfma_f32_16x16x32_bf16(xa[m][ks].v, bt, s4[m][n], 0, 0, 0);
        }

    // ---- softmax per m-tile; write P[i][j] into t1 (T fully consumed above;
    // same-wave program order keeps this safe without a barrier)
#pragma unroll
    for (int m = 0; m < 4; ++m)
#pragma unroll
        for (int r = 0; r < 4; ++r) {
            const int i = m * 16 + lg * 4 + r;
            float v[4], mx = -1e30f;
#pragma unroll
            for (int n = 0; n < 4; ++n) {
                v[n] = s4[m][n][r];
                int j = n * 16 + lr;
                mx = fmaxf(mx, (j < NPIX) ? v[n] : -1e30f);
            }
            mx = fmaxf(mx, __shfl_xor(mx, 1));
            mx = fmaxf(mx, __shfl_xor(mx, 2));
            mx = fmaxf(mx, __shfl_xor(mx, 4));
            mx = fmaxf(mx, __shfl_xor(mx, 8));
            float e[4], sm = 0.f;
#pragma unroll
            for (int n = 0; n < 4; ++n) {
                int j = n * 16 + lr;
                e[n] = (j < NPIX) ? __expf(v[n] - mx) : 0.f;
                sm += e[n];
            }
            sm += __shfl_xor(sm, 1);
            sm += __shfl_xor(sm, 2);
            sm += __shfl_xor(sm, 4);
            sm += __shfl_xor(sm, 8);
            float sinv = 1.0f / sm;
#pragma unroll
            for (int n = 0; n < 4; ++n)
                st1(t1, i, n * 16 + lr, f2b(e[n] * sinv));
        }

    // ---- GEMM3: Yt[i][co] = sum_j P[i][j] F[co][j] ; both operands natural layout
    // Preload F B-frags (m-independent) once.
    bf16x8 fb[2][4];
#pragma unroll
    for (int ks = 0; ks < 2; ++ks)
#pragma unroll
        for (int n = 0; n < 4; ++n)
            fb[ks][n] = ld8(t2, n * 16 + lr, ks * 32 + lg * 8);

    float bias[4];
    const float* ob[4];
#pragma unroll
    for (int n = 0; n < 4; ++n) {
        int co = n * 16 + lr;
        bias[n] = (co < CIN) ? bproj[co] : 0.f;
        ob[n] = out + (size_t)(b * CIN + (co < CIN ? co : 0)) * plane;
    }

#pragma unroll
    for (int m = 0; m < 4; ++m) {
        f32x4 y4[4];
#pragma unroll
        for (int n = 0; n < 4; ++n) y4[n] = fz;
#pragma unroll
        for (int ks = 0; ks < 2; ++ks) {
            bf16x8 ap = ld8(t1, m * 16 + lr, ks * 32 + lg * 8);
#pragma unroll
            for (int n = 0; n < 4; ++n)
                y4[n] = __builtin_amdgcn_mfma_f32_16x16x32_bf16(ap, fb[ks][n], y4[n], 0, 0, 0);
        }
#pragma unroll
        for (int n = 0; n < 4; ++n) {
            int co = n * 16 + lr;
            if (co < CIN) {
#pragma unroll
                for (int r = 0; r < 4; ++r) {
                    int pp = m * 16 + lg * 4 + r;
                    if (pp < NPIX) {
                        int dh = pp / 7, dw = pp - dh * 7;
                        ((float*)ob[n])[(size_t)(h0 + dh) * HW + (w0 + dw)] = y4[n][r] + bias[n];
                    }
                }
            }
        }
    }
}

extern "C" void kernel_launch(void* const* d_in, const int* in_sizes, int n_in,
                              void* d_out, int out_size, void* d_ws, size_t ws_size,
                              hipStream_t stream) {
    const float* x    = (const float*)d_in[0];
    const float* wqkv = (const float*)d_in[1];
    const float* wp   = (const float*)d_in[2];
    const float* bp   = (const float*)d_in[3];
    float* out = (float*)d_out;

    u16* wb = (u16*)d_ws;   // 128*64 bf16: [G = Wq^T Wk /8 ; Wf = Wp Wv]

    prep_weights<<<32, 256, 0, stream>>>(wqkv, wp, wb);
    win_attn<<<8192, 64, 0, stream>>>(x, wb, bp, out);
}

// Round 6
// 125.479 us; speedup vs baseline: 1.2906x; 1.2906x over previous
//
#include <hip/hip_runtime.h>
#include <hip/hip_bf16.h>

typedef __attribute__((ext_vector_type(8))) __bf16 bf16x8;
typedef __attribute__((ext_vector_type(4))) float f32x4;
typedef unsigned short u16;

#define CIN   62
#define HW    224
#define NPIX  49

__device__ __forceinline__ u16 f2b(float f) {
    union { __hip_bfloat16 h; u16 u; } cv;
    cv.h = __float2bfloat16(f);
    return cv.u;
}

// LDS 64x64 bf16 tiles, row stride 64 elems (128B), XOR swizzle on 8-elem (16B) blocks
__device__ __forceinline__ bf16x8 ld8(const u16* buf, int row, int ecol) {
    int idx = (row << 6) + (ecol ^ ((row & 7) << 3));
    return *reinterpret_cast<const bf16x8*>(buf + idx);
}
__device__ __forceinline__ void st1(u16* buf, int row, int ecol, u16 v) {
    buf[(row << 6) + (ecol ^ ((row & 7) << 3))] = v;
}
__device__ __forceinline__ void st4(u16* buf, int row, int ecol, u16 a, u16 b, u16 c, u16 d) {
    int idx = (row << 6) + (ecol ^ ((row & 7) << 3));
    *reinterpret_cast<ushort4*>(buf + idx) = make_ushort4(a, b, c, d);
}

// wb rows 0..63   = G  = Wq^T Wk / 8   (S = X^T G X)
// wb rows 64..127 = Wf = Wp @ Wv       (Y = (Wf X) P^T)
__global__ void prep_weights(const float* __restrict__ wqkv, const float* __restrict__ wp,
                             u16* __restrict__ wb) {
    int t = blockIdx.x * 256 + threadIdx.x;   // 0 .. 128*64-1
    if (t >= 128 * 64) return;
    int o = t >> 6;
    int c = t & 63;
    float s = 0.0f;
    if (o < 64) {
        for (int m = 0; m < 64; ++m)
            s += wqkv[m * 64 + o] * wqkv[(64 + m) * 64 + c];
        s *= 0.125f;
    } else {
        int of = o - 64;
        if (of < CIN)
            for (int m = 0; m < 64; ++m)
                s += wp[of * 64 + m] * wqkv[(128 + m) * 64 + c];
    }
    wb[t] = f2b(s);
}

__global__ __launch_bounds__(256, 6) void win_attn(
    const float* __restrict__ x, const u16* __restrict__ wb,
    const float* __restrict__ bproj, float* __restrict__ out)
{
    __shared__ __align__(16) u16 t1[64 * 64];  // T[j][g]
    __shared__ __align__(16) u16 t2[64 * 64];  // F[co][j]
    __shared__ __align__(16) u16 t3[64 * 64];  // P[i][j]

    const int tid  = threadIdx.x;
    const int lane = tid & 63;
    const int wid  = tid >> 6;
    const int lr   = lane & 15;
    const int lg   = lane >> 4;

    // XCD swizzle: each XCD gets one batch image (1024 consecutive windows)
    const int win = ((blockIdx.x & 7) << 10) | (blockIdx.x >> 3);
    const int b   = win >> 10;
    const int rem = win & 1023;
    const int hn  = rem >> 5;
    const int wn  = rem & 31;
    const int h0  = hn * 7, w0 = wn * 7;

    const size_t plane = (size_t)HW * HW;

    // this wave's pixel (B-frag col for GEMM1 / A-frag row for GEMM2)
    const int p     = wid * 16 + lr;
    const bool valid = p < NPIX;
    const int dh = p / 7, dw = p - dh * 7;
    const int h = h0 + dh, w = w0 + dw;
    const float cx = -1.0f + (2.0f / 223.0f) * (float)w;
    const float cy = -1.0f + (2.0f / 223.0f) * (float)h;
    const float* xp = x + (size_t)b * CIN * plane + (size_t)h * HW + w;

    // ---- X fragment to registers, all 16 loads issued before any use
    float xv[16];
#pragma unroll
    for (int e = 0; e < 16; ++e) {
        int c = (e >> 3) * 32 + lg * 8 + (e & 7);
        float v = 0.0f;
        if (valid)
            v = (c < CIN) ? xp[(size_t)c * plane] : ((c == 62) ? cx : cy);
        xv[e] = v;
    }
    union { bf16x8 v; u16 u[8]; } xa[2];
#pragma unroll
    for (int e = 0; e < 16; ++e) xa[e >> 3].u[e & 7] = f2b(xv[e]);

    const f32x4 fz = {0.f, 0.f, 0.f, 0.f};

    // ---- GEMM1-T: T[all g][wave's 16 px] = G @ X  (8 MFMA), scatter -> t1[j][g]
    {
        f32x4 a1[4];
#pragma unroll
        for (int m = 0; m < 4; ++m) a1[m] = fz;
#pragma unroll
        for (int ks = 0; ks < 2; ++ks)
#pragma unroll
            for (int m = 0; m < 4; ++m) {
                bf16x8 ag = *reinterpret_cast<const bf16x8*>(
                    wb + (m * 16 + lr) * 64 + ks * 32 + lg * 8);
                a1[m] = __builtin_amdgcn_mfma_f32_16x16x32_bf16(ag, xa[ks].v, a1[m], 0, 0, 0);
            }
#pragma unroll
        for (int m = 0; m < 4; ++m)
            st4(t1, p, m * 16 + lg * 4,
                f2b(a1[m][0]), f2b(a1[m][1]), f2b(a1[m][2]), f2b(a1[m][3]));
    }
    __syncthreads();   // B1: t1 (T) complete

    // ---- GEMM2: S[i=wave's px][j] = sum_g X[g][i] T[g][j]; A = xa regs, B = t1
    f32x4 s4[4];
#pragma unroll
    for (int n = 0; n < 4; ++n) s4[n] = fz;
#pragma unroll
    for (int ks = 0; ks < 2; ++ks)
#pragma unroll
        for (int n = 0; n < 4; ++n) {
            bf16x8 bt = ld8(t1, n * 16 + lr, ks * 32 + lg * 8);
            s4[n] = __builtin_amdgcn_mfma_f32_16x16x32_bf16(xa[ks].v, bt, s4[n], 0, 0, 0);
        }

    // ---- GEMM1-F (independent; fills the S->softmax dependency bubble):
    // F[all co][wave's 16 px] = Wf @ X, scatter -> t2[co][j]
    {
        f32x4 a2[4];
#pragma unroll
        for (int m = 0; m < 4; ++m) a2[m] = fz;
#pragma unroll
        for (int ks = 0; ks < 2; ++ks)
#pragma unroll
            for (int m = 0; m < 4; ++m) {
                bf16x8 af = *reinterpret_cast<const bf16x8*>(
                    wb + ((m + 4) * 16 + lr) * 64 + ks * 32 + lg * 8);
                a2[m] = __builtin_amdgcn_mfma_f32_16x16x32_bf16(af, xa[ks].v, a2[m], 0, 0, 0);
            }
#pragma unroll
        for (int m = 0; m < 4; ++m)
#pragma unroll
            for (int r = 0; r < 4; ++r)
                st1(t2, m * 16 + lg * 4 + r, p, f2b(a2[m][r]));
    }

    // ---- register softmax on s4; write P rows (wave-private) into t3
#pragma unroll
    for (int r = 0; r < 4; ++r) {
        const int i = wid * 16 + lg * 4 + r;
        float v[4], mx = -1e30f;
#pragma unroll
        for (int n = 0; n < 4; ++n) {
            v[n] = s4[n][r];
            int j = n * 16 + lr;
            mx = fmaxf(mx, (j < NPIX) ? v[n] : -1e30f);
        }
        mx = fmaxf(mx, __shfl_xor(mx, 1));
        mx = fmaxf(mx, __shfl_xor(mx, 2));
        mx = fmaxf(mx, __shfl_xor(mx, 4));
        mx = fmaxf(mx, __shfl_xor(mx, 8));
        float e[4], sm = 0.f;
#pragma unroll
        for (int n = 0; n < 4; ++n) {
            int j = n * 16 + lr;
            e[n] = (j < NPIX) ? __expf(v[n] - mx) : 0.f;
            sm += e[n];
        }
        sm += __shfl_xor(sm, 1);
        sm += __shfl_xor(sm, 2);
        sm += __shfl_xor(sm, 4);
        sm += __shfl_xor(sm, 8);
        float sinv = 1.0f / sm;
#pragma unroll
        for (int n = 0; n < 4; ++n)
            st1(t3, i, n * 16 + lr, f2b(e[n] * sinv));
    }
    __syncthreads();   // B2: t2 (F) and t3 (P) complete

    // ---- GEMM3: Y[co=wave's tile][p'] = sum_j F[co][j] P[p'][j]; A = t2, B = t3
    f32x4 y4[4];
#pragma unroll
    for (int n = 0; n < 4; ++n) y4[n] = fz;
#pragma unroll
    for (int ks = 0; ks < 2; ++ks) {
        bf16x8 af = ld8(t2, wid * 16 + lr, ks * 32 + lg * 8);
#pragma unroll
        for (int n = 0; n < 4; ++n) {
            bf16x8 bp = ld8(t3, n * 16 + lr, ks * 32 + lg * 8);
            y4[n] = __builtin_amdgcn_mfma_f32_16x16x32_bf16(af, bp, y4[n], 0, 0, 0);
        }
    }

    const int cb = wid * 16 + lg * 4;
    float bias[4];
#pragma unroll
    for (int r = 0; r < 4; ++r) bias[r] = (cb + r < CIN) ? bproj[cb + r] : 0.f;
#pragma unroll
    for (int n = 0; n < 4; ++n) {
        int po = n * 16 + lr;
        if (po < NPIX) {
            int dho = po / 7, dwo = po - dho * 7;
            int ho = h0 + dho, wo = w0 + dwo;
#pragma unroll
            for (int r = 0; r < 4; ++r) {
                int co = cb + r;
                if (co < CIN)
                    out[((b * CIN + co) * HW + ho) * HW + wo] = y4[n][r] + bias[r];
            }
        }
    }
}

extern "C" void kernel_launch(void* const* d_in, const int* in_sizes, int n_in,
                              void* d_out, int out_size, void* d_ws, size_t ws_size,
                              hipStream_t stream) {
    const float* x    = (const float*)d_in[0];
    const float* wqkv = (const float*)d_in[1];
    const float* wp   = (const float*)d_in[2];
    const float* bp   = (const float*)d_in[3];
    float* out = (float*)d_out;

    u16* wb = (u16*)d_ws;   // 128*64 bf16: [G = Wq^T Wk /8 ; Wf = Wp Wv]

    prep_weights<<<32, 256, 0, stream>>>(wqkv, wp, wb);
    win_attn<<<8192, 256, 0, stream>>>(x, wb, bp, out);
}

// Round 7
// 122.600 us; speedup vs baseline: 1.3209x; 1.0235x over previous
//
#include <hip/hip_runtime.h>
#include <hip/hip_bf16.h>

typedef __attribute__((ext_vector_type(8))) __bf16 bf16x8;
typedef __attribute__((ext_vector_type(4))) float f32x4;
typedef unsigned short u16;

#define CIN   62
#define HW    224
#define NPIX  49

__device__ __forceinline__ u16 f2b(float f) {
    union { __hip_bfloat16 h; u16 u; } cv;
    cv.h = __float2bfloat16(f);
    return cv.u;
}

// LDS 64x64 bf16 tiles, row stride 64 elems (128B), XOR swizzle on 8-elem (16B) blocks
__device__ __forceinline__ bf16x8 ld8(const u16* buf, int row, int ecol) {
    int idx = (row << 6) + (ecol ^ ((row & 7) << 3));
    return *reinterpret_cast<const bf16x8*>(buf + idx);
}
__device__ __forceinline__ void st1(u16* buf, int row, int ecol, u16 v) {
    buf[(row << 6) + (ecol ^ ((row & 7) << 3))] = v;
}
__device__ __forceinline__ void st4(u16* buf, int row, int ecol, u16 a, u16 b, u16 c, u16 d) {
    int idx = (row << 6) + (ecol ^ ((row & 7) << 3));
    *reinterpret_cast<ushort4*>(buf + idx) = make_ushort4(a, b, c, d);
}

// wb rows 0..63   = G  = Wq^T Wk / 8   (S = X^T G X)
// wb rows 64..127 = Wf = Wp @ Wv       (Y = (Wf X) P^T)
__global__ void prep_weights(const float* __restrict__ wqkv, const float* __restrict__ wp,
                             u16* __restrict__ wb) {
    int t = blockIdx.x * 256 + threadIdx.x;   // 0 .. 128*64-1
    if (t >= 128 * 64) return;
    int o = t >> 6;
    int c = t & 63;
    float s = 0.0f;
    if (o < 64) {
        for (int m = 0; m < 64; ++m)
            s += wqkv[m * 64 + o] * wqkv[(64 + m) * 64 + c];
        s *= 0.125f;
    } else {
        int of = o - 64;
        if (of < CIN)
            for (int m = 0; m < 64; ++m)
                s += wp[of * 64 + m] * wqkv[(128 + m) * 64 + c];
    }
    wb[t] = f2b(s);
}

// 2-tile / 4-barrier schedule, 16 KB LDS -> 8 blocks/CU (100% occupancy).
// t0: X  -> P (own-row overwrite). t1: T -> F (overwrite after B3).
__global__ __launch_bounds__(256, 8) void win_attn(
    const float* __restrict__ x, const u16* __restrict__ wb,
    const float* __restrict__ bproj, float* __restrict__ out)
{
    __shared__ __align__(16) u16 t0[64 * 64];  // X[p][c] -> P[i][j]
    __shared__ __align__(16) u16 t1[64 * 64];  // T[j][a] -> F[co][j]

    const int tid  = threadIdx.x;
    const int lane = tid & 63;
    const int wid  = tid >> 6;
    const int lr   = lane & 15;
    const int lg   = lane >> 4;

    // XCD swizzle: each XCD gets one batch image (1024 consecutive windows)
    const int win = ((blockIdx.x & 7) << 10) | (blockIdx.x >> 3);
    const int b   = win >> 10;
    const int rem = win & 1023;
    const int hn  = rem >> 5;
    const int wn  = rem & 31;
    const int h0  = hn * 7, w0 = wn * 7;

    const size_t plane = (size_t)HW * HW;

    // ---- stage X[p][c] -> t0 (cooperative, pixel-major coalesced)
    {
        const int p = tid & 63;
        const bool valid = p < NPIX;
        const int dh = p / 7, dw = p - dh * 7;
        const int h = h0 + dh, w = w0 + dw;
        const float cx = -1.0f + (2.0f / 223.0f) * (float)w;
        const float cy = -1.0f + (2.0f / 223.0f) * (float)h;
        const float* xp = x + (size_t)b * CIN * plane + (size_t)h * HW + w;
#pragma unroll
        for (int it = 0; it < 16; ++it) {
            int c = (tid >> 6) + it * 4;
            float v = 0.0f;
            if (valid) {
                if (c < CIN)      v = xp[(size_t)c * plane];
                else if (c == 62) v = cx;
                else              v = cy;
            }
            st1(t0, p, c, f2b(v));
        }
    }
    __syncthreads();   // B1: X staged

    const f32x4 fz = {0.f, 0.f, 0.f, 0.f};
    const int jown = wid * 16 + lr;   // this wave's pixel column (and t0/t1 row)

    // ---- GEMM1-T: T[all a][own 16 px] = G @ X ; B-frags from t0 OWN rows
    {
        f32x4 a1[4];
#pragma unroll
        for (int m = 0; m < 4; ++m) a1[m] = fz;
#pragma unroll
        for (int ks = 0; ks < 2; ++ks) {
            bf16x8 bb = ld8(t0, jown, ks * 32 + lg * 8);
#pragma unroll
            for (int m = 0; m < 4; ++m) {
                bf16x8 ag = *reinterpret_cast<const bf16x8*>(
                    wb + (m * 16 + lr) * 64 + ks * 32 + lg * 8);
                a1[m] = __builtin_amdgcn_mfma_f32_16x16x32_bf16(ag, bb, a1[m], 0, 0, 0);
            }
        }
        // scatter T -> t1[j][a], rows j = own pixels
#pragma unroll
        for (int m = 0; m < 4; ++m)
            st4(t1, jown, m * 16 + lg * 4,
                f2b(a1[m][0]), f2b(a1[m][1]), f2b(a1[m][2]), f2b(a1[m][3]));
    }
    __syncthreads();   // B2: T complete

    // ---- GEMM2: S[own i][all j] = sum_a X^T[i][a] T[j][a]; A = t0 own rows
    f32x4 s4[4];
#pragma unroll
    for (int n = 0; n < 4; ++n) s4[n] = fz;
#pragma unroll
    for (int ks = 0; ks < 2; ++ks) {
        bf16x8 aq = ld8(t0, jown, ks * 32 + lg * 8);
#pragma unroll
        for (int n = 0; n < 4; ++n) {
            bf16x8 bt = ld8(t1, n * 16 + lr, ks * 32 + lg * 8);
            s4[n] = __builtin_amdgcn_mfma_f32_16x16x32_bf16(aq, bt, s4[n], 0, 0, 0);
        }
    }
    __syncthreads();   // B3: all T reads done -> t1 reusable

    // ---- GEMM1-F: F[all co][own px] = Wf @ X (t0 own rows); scatter -> t1[co][j own]
    {
        f32x4 a2[4];
#pragma unroll
        for (int m = 0; m < 4; ++m) a2[m] = fz;
#pragma unroll
        for (int ks = 0; ks < 2; ++ks) {
            bf16x8 bb = ld8(t0, jown, ks * 32 + lg * 8);
#pragma unroll
            for (int m = 0; m < 4; ++m) {
                bf16x8 af = *reinterpret_cast<const bf16x8*>(
                    wb + ((m + 4) * 16 + lr) * 64 + ks * 32 + lg * 8);
                a2[m] = __builtin_amdgcn_mfma_f32_16x16x32_bf16(af, bb, a2[m], 0, 0, 0);
            }
        }
#pragma unroll
        for (int m = 0; m < 4; ++m)
#pragma unroll
            for (int r = 0; r < 4; ++r)
                st1(t1, m * 16 + lg * 4 + r, jown, f2b(a2[m][r]));
    }

    // ---- register softmax on s4; P -> t0 own rows (own X rows dead after GEMM1-F)
#pragma unroll
    for (int r = 0; r < 4; ++r) {
        const int i = wid * 16 + lg * 4 + r;
        float v[4], mx = -1e30f;
#pragma unroll
        for (int n = 0; n < 4; ++n) {
            v[n] = s4[n][r];
            int j = n * 16 + lr;
            mx = fmaxf(mx, (j < NPIX) ? v[n] : -1e30f);
        }
        mx = fmaxf(mx, __shfl_xor(mx, 1));
        mx = fmaxf(mx, __shfl_xor(mx, 2));
        mx = fmaxf(mx, __shfl_xor(mx, 4));
        mx = fmaxf(mx, __shfl_xor(mx, 8));
        float e[4], sm = 0.f;
#pragma unroll
        for (int n = 0; n < 4; ++n) {
            int j = n * 16 + lr;
            e[n] = (j < NPIX) ? __expf(v[n] - mx) : 0.f;
            sm += e[n];
        }
        sm += __shfl_xor(sm, 1);
        sm += __shfl_xor(sm, 2);
        sm += __shfl_xor(sm, 4);
        sm += __shfl_xor(sm, 8);
        float sinv = 1.0f / sm;
#pragma unroll
        for (int n = 0; n < 4; ++n)
            st1(t0, i, n * 16 + lr, f2b(e[n] * sinv));
    }
    __syncthreads();   // B4: F (t1) and P (t0) complete

    // ---- GEMM3: Y[own co][all p'] = sum_j F[co][j] P[p'][j]; A = t1, B = t0
    f32x4 y4[4];
#pragma unroll
    for (int n = 0; n < 4; ++n) y4[n] = fz;
#pragma unroll
    for (int ks = 0; ks < 2; ++ks) {
        bf16x8 af = ld8(t1, wid * 16 + lr, ks * 32 + lg * 8);
#pragma unroll
        for (int n = 0; n < 4; ++n) {
            bf16x8 bp = ld8(t0, n * 16 + lr, ks * 32 + lg * 8);
            y4[n] = __builtin_amdgcn_mfma_f32_16x16x32_bf16(af, bp, y4[n], 0, 0, 0);
        }
    }

    const int cb = wid * 16 + lg * 4;
    float bias[4];
#pragma unroll
    for (int r = 0; r < 4; ++r) bias[r] = (cb + r < CIN) ? bproj[cb + r] : 0.f;
#pragma unroll
    for (int n = 0; n < 4; ++n) {
        int po = n * 16 + lr;
        if (po < NPIX) {
            int dho = po / 7, dwo = po - dho * 7;
            int ho = h0 + dho, wo = w0 + dwo;
#pragma unroll
            for (int r = 0; r < 4; ++r) {
                int co = cb + r;
                if (co < CIN)
                    out[((b * CIN + co) * HW + ho) * HW + wo] = y4[n][r] + bias[r];
            }
        }
    }
}

extern "C" void kernel_launch(void* const* d_in, const int* in_sizes, int n_in,
                              void* d_out, int out_size, void* d_ws, size_t ws_size,
                              hipStream_t stream) {
    const float* x    = (const float*)d_in[0];
    const float* wqkv = (const float*)d_in[1];
    const float* wp   = (const float*)d_in[2];
    const float* bp   = (const float*)d_in[3];
    float* out = (float*)d_out;

    u16* wb = (u16*)d_ws;   // 128*64 bf16: [G = Wq^T Wk /8 ; Wf = Wp Wv]

    prep_weights<<<32, 256, 0, stream>>>(wqkv, wp, wb);
    win_attn<<<8192, 256, 0, stream>>>(x, wb, bp, out);
}